// Round 10
// baseline (594.093 us; speedup 1.0000x reference)
//
#include <hip/hip_runtime.h>
#include <hip/hip_bf16.h>

#define NB    16
#define CIN   512
#define COUT  512
#define HH    64
#define WW    64
#define HWSZ  4096
#define WDIMN 512

typedef __attribute__((ext_vector_type(8))) short bf16x8;
typedef __attribute__((ext_vector_type(4))) float f32x4;

__device__ __forceinline__ unsigned short f2bf(float f) {
    unsigned int u = __float_as_uint(f);
    unsigned int lsb = (u >> 16) & 1u;
    u += 0x7fffu + lsb;               // round-to-nearest-even (finite inputs)
    return (unsigned short)(u >> 16);
}

__device__ __forceinline__ void gload_lds16(const void* g, void* l) {
    __builtin_amdgcn_global_load_lds(
        (const __attribute__((address_space(1))) unsigned char*)g,
        (__attribute__((address_space(3))) unsigned char*)l,
        16, 0, 0);
}

// ---------------- k1: style[b][ci] = coef_mod * (w @ mod_w) + mod_b + 1 ----------------
__global__ void k_style(const float* __restrict__ w, const float* __restrict__ mod_w,
                        const float* __restrict__ mod_b, float* __restrict__ style) {
    const int b = blockIdx.x, t = threadIdx.x;
    __shared__ float wl[WDIMN];
    wl[t] = w[b * WDIMN + t];
    wl[t + 256] = w[b * WDIMN + t + 256];
    __syncthreads();
    float a0 = 0.f, a1 = 0.f;
    const int c0 = t, c1 = t + 256;
    for (int j = 0; j < WDIMN; ++j) {
        const float wj = wl[j];
        a0 += wj * mod_w[j * CIN + c0];
        a1 += wj * mod_w[j * CIN + c1];
    }
    const float coef = 0.044194173824159216f; // 1/sqrt(512)
    style[b * CIN + c0] = coef * a0 + mod_b[c0] + 1.0f;
    style[b * CIN + c1] = coef * a1 + mod_b[c1] + 1.0f;
}

// ---------------- k2: s2[ci][co] = sum_taps conv_w^2 ----------------
__global__ void k_s2(const float* __restrict__ cw, float* __restrict__ s2) {
    const int i = blockIdx.x * 256 + threadIdx.x; // [ci*512+co]
    float a = 0.f;
#pragma unroll
    for (int tap = 0; tap < 9; ++tap) {
        const float v = cw[tap * (CIN * COUT) + i];
        a += v * v;
    }
    s2[i] = a;
}

// ---------------- k3: d[b][co] = rsqrt(coef^2 * sum_ci style^2 * s2 + 1e-8) ----------------
__global__ void k_demod(const float* __restrict__ style, const float* __restrict__ s2,
                        float* __restrict__ dd) {
    const int b = blockIdx.x, t = threadIdx.x;
    __shared__ float st2[CIN];
    {
        const float s0 = style[b * CIN + t], s1 = style[b * CIN + t + 256];
        st2[t] = s0 * s0;
        st2[t + 256] = s1 * s1;
    }
    __syncthreads();
    float a0 = 0.f, a1 = 0.f;
    for (int ci = 0; ci < CIN; ++ci) {
        const float sv = st2[ci];
        a0 += sv * s2[ci * COUT + t];
        a1 += sv * s2[ci * COUT + t + 256];
    }
    const float c2 = 1.0f / 4608.0f; // coef_conv^2
    dd[b * COUT + t] = rsqrtf(c2 * a0 + 1e-8f);
    dd[b * COUT + t + 256] = rsqrtf(c2 * a1 + 1e-8f);
}

// ---------------- k4: wmod[bbl][tap][co][ci] = bf16(conv_w * coef * style * d) ----------------
__global__ void k_wmod(const float* __restrict__ cw, const float* __restrict__ style,
                       const float* __restrict__ dd, unsigned short* __restrict__ wmod,
                       int b_start, int gcount) {
    const int tap = blockIdx.x;
    const int co0 = blockIdx.y * 64;
    const int ci0 = blockIdx.z * 128;
    const int t = threadIdx.x;

    __shared__ float tile[128][65]; // [ci][co], padded
    __shared__ float sst[16 * 128]; // style slice [bbl][128-ci-chunk]
    {
        const int j = t & 63, isub = t >> 6;
        for (int i = isub; i < 128; i += 4)
            tile[i][j] = cw[(size_t)tap * CIN * COUT + (size_t)(ci0 + i) * COUT + co0 + j];
    }
    for (int i = t; i < gcount * 128; i += 256)
        sst[i] = style[(b_start + (i >> 7)) * CIN + ci0 + (i & 127)];
    __syncthreads();

    const float coef = 0.014731391274719736f; // 1/sqrt(4608)
    const int cq = t & 31;        // ci quad: ci = ci0 + 4*cq + k
    const int rsub = t >> 5;      // 0..7
    const int totrows = gcount * 64;
    for (int g = rsub; g < totrows; g += 8) {
        const int bbl = g >> 6;
        const int co_r = g & 63;
        const int bg = b_start + bbl;
        const float dv = dd[bg * COUT + co0 + co_r] * coef;
        const float v0 = tile[4 * cq + 0][co_r] * sst[bbl * 128 + 4 * cq + 0] * dv;
        const float v1 = tile[4 * cq + 1][co_r] * sst[bbl * 128 + 4 * cq + 1] * dv;
        const float v2 = tile[4 * cq + 2][co_r] * sst[bbl * 128 + 4 * cq + 2] * dv;
        const float v3 = tile[4 * cq + 3][co_r] * sst[bbl * 128 + 4 * cq + 3] * dv;
        uint2 pk;
        pk.x = (unsigned int)f2bf(v0) | ((unsigned int)f2bf(v1) << 16);
        pk.y = (unsigned int)f2bf(v2) | ((unsigned int)f2bf(v3) << 16);
        *(uint2*)&wmod[((size_t)(bbl * 9 + tap) * COUT + co0 + co_r) * CIN + ci0 + 4 * cq] = pk;
    }
}

// ---------------- k5: xT[bbl][hw][ci] = bf16(x[b][ci][hw]) ---------------- (8B stores)
__global__ void k_xt(const float* __restrict__ x, unsigned short* __restrict__ xT, int b_start) {
    const int bbl = blockIdx.x;
    const int b = b_start + bbl;
    const int hw0 = blockIdx.y * 64;
    const int ci0 = blockIdx.z * 64;
    const int t = threadIdx.x;

    __shared__ float tile[64][65]; // [ci][hw], padded
    {
        const int j = t & 63, isub = t >> 6;
        for (int i = isub; i < 64; i += 4)
            tile[i][j] = x[((size_t)b * CIN + ci0 + i) * HWSZ + hw0 + j];
    }
    __syncthreads();

    const int cq = t & 15;   // ci quad within 64-chunk
    const int rs = t >> 4;   // 0..15
    for (int r = rs; r < 64; r += 16) {
        const float v0 = tile[4 * cq + 0][r];
        const float v1 = tile[4 * cq + 1][r];
        const float v2 = tile[4 * cq + 2][r];
        const float v3 = tile[4 * cq + 3][r];
        uint2 pk;
        pk.x = (unsigned int)f2bf(v0) | ((unsigned int)f2bf(v1) << 16);
        pk.y = (unsigned int)f2bf(v2) | ((unsigned int)f2bf(v3) << 16);
        *(uint2*)&xT[((size_t)bbl * HWSZ + hw0 + r) * CIN + ci0 + 4 * cq] = pk;
    }
}

// ---------------- k6: 9-tap implicit-GEMM conv, 256co x 256px, round-6 sync ----------
// 512 threads (8 waves: wrow 0..3 co-quarter, wcol 0..1 px-half of 64co x 128px each).
// Tile: 256 co x 256 px (4 rows x 64 cols), BK=64 over ci, 9 taps per ci-chunk.
// X halo [6 rows][66 cols][128B] single buffer; A [256co][128B] double-buffered.
// Sync: EXACT round-6 counted-vmcnt scheme (per-wave issue counts identical: stageA=4,
// stageX<=6 -> vmcnt(4) always leaves exactly A(g+2) in flight).
#define AS_OFF (6 * 66 * 128)
__global__ __launch_bounds__(512, 2)
void k_conv(const unsigned short* __restrict__ xT, const unsigned short* __restrict__ wmod,
            float* __restrict__ out, int b_start, int gcount) {
    int st, ct, bbl;
    {
        const int id = blockIdx.x;
        if (gcount == 16) {
            // pin bbl (and its xT/wmod panels) to one XCD L2
            const int xcd = id & 7;
            const int slot = id >> 3;          // 0..63
            bbl = xcd + 8 * (slot >> 5);       // {xcd, xcd+8}
            const int rem = slot & 31;
            ct = rem >> 4;                     // 0..1
            st = rem & 15;                     // 0..15
        } else {
            st = id & 15; ct = (id >> 4) & 1; bbl = id >> 5;
        }
    }
    const int b = b_start + bbl;
    const int r0 = st * 4;      // first output row (4 rows per tile)
    const int co0 = ct * 256;

    const int t = threadIdx.x;
    const int lane = t & 63;
    const int wid = t >> 6;     // 0..7
    const int wrow = wid >> 1;  // 0..3: co quarter (64 co)
    const int wcol = wid & 1;   // 0..1: px half (2 rows x 64 cols)

    __shared__ __align__(16) unsigned char smem[AS_OFF + 2 * 32768]; // 113.5 KiB
    unsigned char* Xs = smem;            // [(row*66+col)][128B], XOR-swizzled
    unsigned char* As = smem + AS_OFF;   // 2 x [256co][128B]

    const f32x4 fzero = {0.f, 0.f, 0.f, 0.f};

    // one-time zeroing: pad columns (0, 65) for all 6 rows, and out-of-image halo rows
    if (t < 96) {
        const int s = t >> 3;                    // 12 pad slots
        const int row = s >> 1, col = (s & 1) ? 65 : 0;
        *(f32x4*)(Xs + (row * 66 + col) * 128 + (t & 7) * 16) = fzero;
    }
    if (r0 == 0) {
        for (int idx = t; idx < 66 * 8; idx += 512)
            *(f32x4*)(Xs + (idx >> 3) * 128 + (idx & 7) * 16) = fzero;
    }
    if (r0 == 60) {
        for (int idx = t; idx < 66 * 8; idx += 512)
            *(f32x4*)(Xs + (5 * 66 + (idx >> 3)) * 128 + (idx & 7) * 16) = fzero;
    }

    f32x4 acc[4][8];
#pragma unroll
    for (int i = 0; i < 4; ++i)
#pragma unroll
        for (int j = 0; j < 8; ++j) acc[i][j] = fzero;

    const size_t xTbase = (size_t)bbl * HWSZ * CIN;

    auto stageA = [&](int gidx) { // load A(gidx) into slot gidx&1 (4 issues/wave)
        const int tap2 = gidx % 9, cc2 = gidx / 9;
        const unsigned short* gb = wmod + ((size_t)(bbl * 9 + tap2) * COUT + co0) * CIN + cc2 * 64;
        unsigned char* dbase = As + (gidx & 1) * 32768;
#pragma unroll
        for (int i = 0; i < 4; ++i) {
            const int la = wid + 8 * i;                 // 0..31
            const int row = la * 8 + (lane >> 3);       // 0..255 (co)
            const int kb = ((lane & 7) * 16) ^ ((row & 7) << 4); // pre-swizzled source
            gload_lds16((const unsigned char*)(gb + (size_t)row * CIN) + kb,
                        dbase + la * 1024);
        }
    };
    auto stageX = [&](int ccn) { // 6 rows x 64 cols; <=6 issues/wave (one per row)
        const int ci0 = ccn * 64;
#pragma unroll
        for (int i = 0; i < 6; ++i) {
            const int li = wid + 8 * i;      // 0..47
            const int row = li >> 3;         // 0..5 (== i for wid<8)
            const int c0 = 1 + (li & 7) * 8; // 1,9,...,57
            const int ih = r0 - 1 + row;
            if (ih >= 0 && ih < HH) {
                const int col = c0 + (lane >> 3);     // 1..64
                const int pxidx = row * 66 + col;
                const int kb = ((lane & 7) * 16) ^ ((pxidx & 7) << 4);
                gload_lds16((const unsigned char*)(xT + xTbase + (size_t)(ih * WW + col - 1) * CIN + ci0) + kb,
                            Xs + (row * 66 + c0) * 128);
            }
        }
    };

    // prologue: X(0), A(0), A(1); wait X+A(0) (A(1) may fly) + own zero-fill; barrier
    stageX(0);
    stageA(0);
    stageA(1);
    asm volatile("s_waitcnt vmcnt(4) lgkmcnt(0)" ::: "memory");
    __builtin_amdgcn_s_barrier();

    for (int cc = 0; cc < 8; ++cc) {
#pragma unroll
        for (int tap = 0; tap < 9; ++tap) {
            const int g = cc * 9 + tap;
            const unsigned char* Ab = As + (g & 1) * 32768;
            const int dh = tap / 3 - 1, dw = tap % 3 - 1;

            // ds_read + MFMA, compiler-scheduled (fine-grained lgkmcnt interleave)
#pragma unroll
            for (int k32 = 0; k32 < 2; ++k32) {
                bf16x8 af[4], bfv[8];
#pragma unroll
                for (int ma = 0; ma < 4; ++ma) {
                    const int co_r = wrow * 64 + ma * 16 + (lane & 15);
                    const int kb = (k32 * 64 + (lane >> 4) * 16) ^ ((co_r & 7) << 4);
                    af[ma] = *(const bf16x8*)(Ab + co_r * 128 + kb);
                }
#pragma unroll
                for (int nb = 0; nb < 8; ++nb) {
                    const int px = nb * 16 + (lane & 15);      // 0..127 local
                    const int trow = (px >> 6) + 2 * wcol + 1 + dh; // 0..5
                    const int tcol = (px & 63) + 1 + dw;            // 0..65
                    const int pxidx = trow * 66 + tcol;
                    const int kb = (k32 * 64 + (lane >> 4) * 16) ^ ((pxidx & 7) << 4);
                    bfv[nb] = *(const bf16x8*)(Xs + pxidx * 128 + kb);
                }
#pragma unroll
                for (int ma = 0; ma < 4; ++ma)
#pragma unroll
                    for (int nb = 0; nb < 8; ++nb)
                        acc[ma][nb] = __builtin_amdgcn_mfma_f32_16x16x32_bf16(
                            af[ma], bfv[nb], acc[ma][nb], 0, 0, 0);
            }

            // barrier #1: this wave's LDS reads retired; all waves done with slot/Xs
            asm volatile("s_waitcnt lgkmcnt(0)" ::: "memory");
            __builtin_amdgcn_s_barrier();

            // prefetch: X(cc+1) first (so vmcnt(4) covers it), then A(g+2) into slot g&1
            if (tap == 8 && cc < 7) stageX(cc + 1);
            if (g < 70) stageA(g + 2);

            // wait: A(g+1) (+X if boundary) landed; A(g+2) stays in flight
            if (g == 70) asm volatile("s_waitcnt vmcnt(0)" ::: "memory");
            else         asm volatile("s_waitcnt vmcnt(4)" ::: "memory");
            __builtin_amdgcn_s_barrier();   // barrier #2: next operands visible to all
        }
    }

    // epilogue: C/D layout col=lane&15 (px/N), row=(lane>>4)*4+reg (co/M)
#pragma unroll
    for (int ma = 0; ma < 4; ++ma) {
        const int co = co0 + wrow * 64 + ma * 16 + ((lane >> 4) << 2);
#pragma unroll
        for (int nb = 0; nb < 8; ++nb) {
            const int px = nb * 16 + (lane & 15);
            const int oh = r0 + 2 * wcol + (px >> 6);
            const int ow = px & 63;
            float* o = out + (((size_t)b * COUT + co) * HH + oh) * WW + ow;
#pragma unroll
            for (int jj = 0; jj < 4; ++jj) o[(size_t)jj * HWSZ] = acc[ma][nb][jj];
        }
    }
}

extern "C" void kernel_launch(void* const* d_in, const int* in_sizes, int n_in,
                              void* d_out, int out_size, void* d_ws, size_t ws_size,
                              hipStream_t stream) {
    (void)in_sizes; (void)n_in; (void)out_size;
    const float* x     = (const float*)d_in[0];
    const float* w     = (const float*)d_in[1];
    const float* convw = (const float*)d_in[2];
    const float* mod_w = (const float*)d_in[3];
    const float* mod_b = (const float*)d_in[4];
    float* out = (float*)d_out;

    unsigned char* ws = (unsigned char*)d_ws;
    const size_t OFF_STYLE = 0;
    const size_t OFF_S2 = 32768;
    const size_t OFF_D = OFF_S2 + 1048576;
    const size_t OFF_BIG = OFF_D + 32768;
    const size_t PER_B_W = (size_t)9 * COUT * CIN * 2; // 4,718,592 B
    const size_t PER_B_X = (size_t)HWSZ * CIN * 2;     // 4,194,304 B
    const size_t PER_B = PER_B_W + PER_B_X;

    if (ws_size < OFF_BIG + PER_B) return; // cannot run
    const size_t avail = ws_size - OFF_BIG;
    const int G = (avail >= 16 * PER_B) ? 16 : (avail >= 4 * PER_B ? 4 : 1);

    float* style = (float*)(ws + OFF_STYLE);
    float* s2    = (float*)(ws + OFF_S2);
    float* dd    = (float*)(ws + OFF_D);
    unsigned short* wmod = (unsigned short*)(ws + OFF_BIG);
    unsigned short* xT   = (unsigned short*)(ws + OFF_BIG + (size_t)G * PER_B_W);

    k_style<<<dim3(16), dim3(256), 0, stream>>>(w, mod_w, mod_b, style);
    k_s2<<<dim3(1024), dim3(256), 0, stream>>>(convw, s2);
    k_demod<<<dim3(16), dim3(256), 0, stream>>>(style, s2, dd);

    for (int b0 = 0; b0 < NB; b0 += G) {
        k_wmod<<<dim3(9, 8, 4), dim3(256), 0, stream>>>(convw, style, dd, wmod, b0, G);
        k_xt<<<dim3(G, 64, 8), dim3(256), 0, stream>>>(x, xT, b0);
        k_conv<<<dim3(16 * 2 * G), dim3(512), 0, stream>>>(xT, wmod, out, b0, G);
    }
}

// Round 11
// 436.270 us; speedup vs baseline: 1.3618x; 1.3618x over previous
//
#include <hip/hip_runtime.h>
#include <hip/hip_bf16.h>

#define NB    16
#define CIN   512
#define COUT  512
#define HH    64
#define WW    64
#define HWSZ  4096
#define WDIMN 512

typedef __attribute__((ext_vector_type(8))) short bf16x8;
typedef __attribute__((ext_vector_type(4))) float f32x4;

__device__ __forceinline__ unsigned short f2bf(float f) {
    unsigned int u = __float_as_uint(f);
    unsigned int lsb = (u >> 16) & 1u;
    u += 0x7fffu + lsb;               // round-to-nearest-even (finite inputs)
    return (unsigned short)(u >> 16);
}

__device__ __forceinline__ void gload_lds16(const void* g, void* l) {
    __builtin_amdgcn_global_load_lds(
        (const __attribute__((address_space(1))) unsigned char*)g,
        (__attribute__((address_space(3))) unsigned char*)l,
        16, 0, 0);
}

// ---------------- k1: style[b][ci] = coef_mod * (w @ mod_w) + mod_b + 1 ----------------
__global__ void k_style(const float* __restrict__ w, const float* __restrict__ mod_w,
                        const float* __restrict__ mod_b, float* __restrict__ style) {
    const int b = blockIdx.x, t = threadIdx.x;
    __shared__ float wl[WDIMN];
    wl[t] = w[b * WDIMN + t];
    wl[t + 256] = w[b * WDIMN + t + 256];
    __syncthreads();
    float a0 = 0.f, a1 = 0.f;
    const int c0 = t, c1 = t + 256;
    for (int j = 0; j < WDIMN; ++j) {
        const float wj = wl[j];
        a0 += wj * mod_w[j * CIN + c0];
        a1 += wj * mod_w[j * CIN + c1];
    }
    const float coef = 0.044194173824159216f; // 1/sqrt(512)
    style[b * CIN + c0] = coef * a0 + mod_b[c0] + 1.0f;
    style[b * CIN + c1] = coef * a1 + mod_b[c1] + 1.0f;
}

// ---------------- k2: s2[ci][co] = sum_taps conv_w^2 ----------------
__global__ void k_s2(const float* __restrict__ cw, float* __restrict__ s2) {
    const int i = blockIdx.x * 256 + threadIdx.x; // [ci*512+co]
    float a = 0.f;
#pragma unroll
    for (int tap = 0; tap < 9; ++tap) {
        const float v = cw[tap * (CIN * COUT) + i];
        a += v * v;
    }
    s2[i] = a;
}

// ---------------- k3: d[b][co] = rsqrt(coef^2 * sum_ci style^2 * s2 + 1e-8) ----------------
__global__ void k_demod(const float* __restrict__ style, const float* __restrict__ s2,
                        float* __restrict__ dd) {
    const int b = blockIdx.x, t = threadIdx.x;
    __shared__ float st2[CIN];
    {
        const float s0 = style[b * CIN + t], s1 = style[b * CIN + t + 256];
        st2[t] = s0 * s0;
        st2[t + 256] = s1 * s1;
    }
    __syncthreads();
    float a0 = 0.f, a1 = 0.f;
    for (int ci = 0; ci < CIN; ++ci) {
        const float sv = st2[ci];
        a0 += sv * s2[ci * COUT + t];
        a1 += sv * s2[ci * COUT + t + 256];
    }
    const float c2 = 1.0f / 4608.0f; // coef_conv^2
    dd[b * COUT + t] = rsqrtf(c2 * a0 + 1e-8f);
    dd[b * COUT + t + 256] = rsqrtf(c2 * a1 + 1e-8f);
}

// ---------------- k4: wmod[bbl][tap][co][ci] = bf16(conv_w * coef * style * d) ----------------
__global__ void k_wmod(const float* __restrict__ cw, const float* __restrict__ style,
                       const float* __restrict__ dd, unsigned short* __restrict__ wmod,
                       int b_start, int gcount) {
    const int tap = blockIdx.x;
    const int co0 = blockIdx.y * 64;
    const int ci0 = blockIdx.z * 128;
    const int t = threadIdx.x;

    __shared__ float tile[128][65]; // [ci][co], padded
    __shared__ float sst[16 * 128]; // style slice [bbl][128-ci-chunk]
    {
        const int j = t & 63, isub = t >> 6;
        for (int i = isub; i < 128; i += 4)
            tile[i][j] = cw[(size_t)tap * CIN * COUT + (size_t)(ci0 + i) * COUT + co0 + j];
    }
    for (int i = t; i < gcount * 128; i += 256)
        sst[i] = style[(b_start + (i >> 7)) * CIN + ci0 + (i & 127)];
    __syncthreads();

    const float coef = 0.014731391274719736f; // 1/sqrt(4608)
    const int cq = t & 31;        // ci quad: ci = ci0 + 4*cq + k
    const int rsub = t >> 5;      // 0..7
    const int totrows = gcount * 64;
    for (int g = rsub; g < totrows; g += 8) {
        const int bbl = g >> 6;
        const int co_r = g & 63;
        const int bg = b_start + bbl;
        const float dv = dd[bg * COUT + co0 + co_r] * coef;
        const float v0 = tile[4 * cq + 0][co_r] * sst[bbl * 128 + 4 * cq + 0] * dv;
        const float v1 = tile[4 * cq + 1][co_r] * sst[bbl * 128 + 4 * cq + 1] * dv;
        const float v2 = tile[4 * cq + 2][co_r] * sst[bbl * 128 + 4 * cq + 2] * dv;
        const float v3 = tile[4 * cq + 3][co_r] * sst[bbl * 128 + 4 * cq + 3] * dv;
        uint2 pk;
        pk.x = (unsigned int)f2bf(v0) | ((unsigned int)f2bf(v1) << 16);
        pk.y = (unsigned int)f2bf(v2) | ((unsigned int)f2bf(v3) << 16);
        *(uint2*)&wmod[((size_t)(bbl * 9 + tap) * COUT + co0 + co_r) * CIN + ci0 + 4 * cq] = pk;
    }
}

// ---------------- k5: xT[bbl][hw][ci] = bf16(x[b][ci][hw]) ----------------
// float4 global reads (16B/lane), scalar LDS writes, proven transpose/write phase.
__global__ void k_xt(const float* __restrict__ x, unsigned short* __restrict__ xT, int b_start) {
    const int bbl = blockIdx.x;
    const int b = b_start + bbl;
    const int hw0 = blockIdx.y * 64;
    const int ci0 = blockIdx.z * 64;
    const int t = threadIdx.x;

    __shared__ float tile[64][65]; // [ci][hw], padded
    {
        const int q = t & 15;      // hw quad (4 floats)
        const int i0 = t >> 4;     // 0..15
        for (int i = i0; i < 64; i += 16) {
            const float4 v = *(const float4*)&x[(size_t)(b * CIN + ci0 + i) * HWSZ + hw0 + 4 * q];
            tile[i][4 * q + 0] = v.x;
            tile[i][4 * q + 1] = v.y;
            tile[i][4 * q + 2] = v.z;
            tile[i][4 * q + 3] = v.w;
        }
    }
    __syncthreads();

    const int cq = t & 15;   // ci quad within 64-chunk
    const int rs = t >> 4;   // 0..15
    for (int r = rs; r < 64; r += 16) {
        const float v0 = tile[4 * cq + 0][r];
        const float v1 = tile[4 * cq + 1][r];
        const float v2 = tile[4 * cq + 2][r];
        const float v3 = tile[4 * cq + 3][r];
        uint2 pk;
        pk.x = (unsigned int)f2bf(v0) | ((unsigned int)f2bf(v1) << 16);
        pk.y = (unsigned int)f2bf(v2) | ((unsigned int)f2bf(v3) << 16);
        *(uint2*)&xT[((size_t)bbl * HWSZ + hw0 + r) * CIN + ci0 + 4 * cq] = pk;
    }
}

// ---------------- k6: 9-tap implicit-GEMM conv, 128co x 256px, round-6 sync ----------
// 256 threads, 4 waves: wrow=wid>>1 picks 64-co half, wcol=wid&1 picks 2-row px half.
// Tile: 128 co x 256 px (4 rows x 64 cols), BK=64, 9 taps per ci-chunk.
// LDS: X halo [6 rows][64 cols][128B] (NO pad cols — dw=+-1 boundary via clamp+zero,
// compile-time per unrolled tap) + A dbuf 2x16KB = 81920 B exactly -> 2 blocks/CU.
// Sync: EXACT round-6 counted-vmcnt scheme (stageA=4/wave, stageX=12/wave uniform,
// vmcnt(4) always leaves exactly A(g+2) in flight). T5 setprio around MFMA cluster.
#define XROWB 8192                    // 64 cols * 128 B
#define AS_OFF (6 * XROWB)            // 49152
__global__ __launch_bounds__(256, 2)
void k_conv(const unsigned short* __restrict__ xT, const unsigned short* __restrict__ wmod,
            float* __restrict__ out, int b_start, int gcount) {
    int st, ct, bbl;
    {
        const int id = blockIdx.x;
        if (gcount == 16) {
            // pin bbl (and its xT/wmod panels) to one XCD L2
            const int xcd = id & 7;
            const int slot = id >> 3;          // 0..127
            bbl = xcd + 8 * (slot >> 6);       // {xcd, xcd+8}
            const int rem = slot & 63;
            ct = rem >> 4;                     // 0..3
            st = rem & 15;                     // 0..15
        } else {
            st = id & 15; ct = (id >> 4) & 3; bbl = id >> 6;
        }
    }
    const int b = b_start + bbl;
    const int r0 = st * 4;      // first output row (4 rows per tile)
    const int co0 = ct * 128;

    const int t = threadIdx.x;
    const int lane = t & 63;
    const int wid = t >> 6;     // 0..3
    const int wrow = wid >> 1;  // 0..1: co half (64 co)
    const int wcol = wid & 1;   // 0..1: px half (2 rows x 64 cols)

    __shared__ __align__(16) unsigned char smem[AS_OFF + 2 * 16384]; // 81920 B exactly
    unsigned char* Xs = smem;            // [(row*64+col)][128B], XOR-swizzled
    unsigned char* As = smem + AS_OFF;   // 2 x [128co][128B]

    const f32x4 fzero = {0.f, 0.f, 0.f, 0.f};
    const bf16x8 zero8 = {0, 0, 0, 0, 0, 0, 0, 0};

    // zero out-of-image halo rows (full 64-col rows)
    if (r0 == 0) {
        for (int idx = t; idx < 64 * 8; idx += 256)
            *(f32x4*)(Xs + (idx >> 3) * 128 + (idx & 7) * 16) = fzero;
    }
    if (r0 == 60) {
        for (int idx = t; idx < 64 * 8; idx += 256)
            *(f32x4*)(Xs + 5 * XROWB + (idx >> 3) * 128 + (idx & 7) * 16) = fzero;
    }

    f32x4 acc[4][8];
#pragma unroll
    for (int i = 0; i < 4; ++i)
#pragma unroll
        for (int j = 0; j < 8; ++j) acc[i][j] = fzero;

    const size_t xTbase = (size_t)bbl * HWSZ * CIN;

    auto stageA = [&](int gidx) { // load A(gidx) into slot gidx&1 (4 issues/wave)
        const int tap2 = gidx % 9, cc2 = gidx / 9;
        const unsigned short* gb = wmod + ((size_t)(bbl * 9 + tap2) * COUT + co0) * CIN + cc2 * 64;
        unsigned char* dbase = As + (gidx & 1) * 16384;
#pragma unroll
        for (int i = 0; i < 4; ++i) {
            const int la = wid + 4 * i;                 // 0..15
            const int row = la * 8 + (lane >> 3);       // 0..127 (co)
            const int kb = ((lane & 7) * 16) ^ ((row & 7) << 4); // pre-swizzled source
            gload_lds16((const unsigned char*)(gb + (size_t)row * CIN) + kb,
                        dbase + la * 1024);
        }
    };
    auto stageX = [&](int ccn) { // 6 rows x 64 cols; 12 issues/wave (uniform)
        const int ci0 = ccn * 64;
#pragma unroll
        for (int i = 0; i < 12; ++i) {
            const int li = wid + 4 * i;      // 0..47
            const int row = li >> 3;         // 0..5
            const int c0 = (li & 7) * 8;     // 0,8,...,56
            const int ih = r0 - 1 + row;
            if (ih >= 0 && ih < HH) {        // wave-uniform skip (2/wave at edges)
                const int col = c0 + (lane >> 3);     // 0..63 == iw
                const int pxidx = row * 64 + col;
                const int kb = ((lane & 7) * 16) ^ ((pxidx & 7) << 4);
                gload_lds16((const unsigned char*)(xT + xTbase + (size_t)(ih * WW + col) * CIN + ci0) + kb,
                            Xs + (row * 64 + c0) * 128);
            }
        }
    };

    // prologue: X(0), A(0), A(1); wait X+A(0) (A(1) may fly) + own zero-fill; barrier
    stageX(0);
    stageA(0);
    stageA(1);
    asm volatile("s_waitcnt vmcnt(4) lgkmcnt(0)" ::: "memory");
    __builtin_amdgcn_s_barrier();

    for (int cc = 0; cc < 8; ++cc) {
#pragma unroll
        for (int tap = 0; tap < 9; ++tap) {
            const int g = cc * 9 + tap;
            const unsigned char* Ab = As + (g & 1) * 16384;
            const int dh = tap / 3 - 1, dw = tap % 3 - 1;   // compile-time (tap unrolled)

            // ds_read + MFMA, compiler-scheduled (fine-grained lgkmcnt interleave)
#pragma unroll
            for (int k32 = 0; k32 < 2; ++k32) {
                bf16x8 af[4], bfv[8];
#pragma unroll
                for (int ma = 0; ma < 4; ++ma) {
                    const int co_r = wrow * 64 + ma * 16 + (lane & 15);
                    const int kb = (k32 * 64 + (lane >> 4) * 16) ^ ((co_r & 7) << 4);
                    af[ma] = *(const bf16x8*)(Ab + co_r * 128 + kb);
                }
#pragma unroll
                for (int nb = 0; nb < 8; ++nb) {
                    const int pxl = nb * 16 + (lane & 15);          // 0..127 local px
                    const int trow = (wcol << 1) + (pxl >> 6) + 1 + dh; // 0..5
                    const int ow = pxl & 63;
                    const int iw = ow + dw;
                    const int iwc = iw < 0 ? 0 : (iw > 63 ? 63 : iw);
                    const int pxidx = trow * 64 + iwc;
                    const int kb = (k32 * 64 + (lane >> 4) * 16) ^ ((iwc & 7) << 4);
                    bf16x8 v = *(const bf16x8*)(Xs + pxidx * 128 + kb);
                    if (dw != 0 && iw != iwc) v = zero8;  // w-boundary: zero contribution
                    bfv[nb] = v;
                }
                __builtin_amdgcn_s_setprio(1);
#pragma unroll
                for (int ma = 0; ma < 4; ++ma)
#pragma unroll
                    for (int nb = 0; nb < 8; ++nb)
                        acc[ma][nb] = __builtin_amdgcn_mfma_f32_16x16x32_bf16(
                            af[ma], bfv[nb], acc[ma][nb], 0, 0, 0);
                __builtin_amdgcn_s_setprio(0);
            }

            // barrier #1: this wave's LDS reads retired; all waves done with slot/Xs
            asm volatile("s_waitcnt lgkmcnt(0)" ::: "memory");
            __builtin_amdgcn_s_barrier();

            // prefetch: X(cc+1) first (so vmcnt(4) covers it), then A(g+2) into slot g&1
            if (tap == 8 && cc < 7) stageX(cc + 1);
            if (g < 70) stageA(g + 2);

            // wait: A(g+1) (+X if boundary) landed; A(g+2) stays in flight
            if (g == 70) asm volatile("s_waitcnt vmcnt(0)" ::: "memory");
            else         asm volatile("s_waitcnt vmcnt(4)" ::: "memory");
            __builtin_amdgcn_s_barrier();   // barrier #2: next operands visible to all
        }
    }

    // epilogue: C/D layout col=lane&15 (px/N), row=(lane>>4)*4+reg (co/M)
#pragma unroll
    for (int ma = 0; ma < 4; ++ma) {
        const int co = co0 + wrow * 64 + ma * 16 + ((lane >> 4) << 2);
#pragma unroll
        for (int nb = 0; nb < 8; ++nb) {
            const int pxl = nb * 16 + (lane & 15);
            const int oh = r0 + (wcol << 1) + (nb >> 2);
            const int ow = pxl & 63;
            float* o = out + (((size_t)b * COUT + co) * HH + oh) * WW + ow;
#pragma unroll
            for (int jj = 0; jj < 4; ++jj) o[(size_t)jj * HWSZ] = acc[ma][nb][jj];
        }
    }
}

extern "C" void kernel_launch(void* const* d_in, const int* in_sizes, int n_in,
                              void* d_out, int out_size, void* d_ws, size_t ws_size,
                              hipStream_t stream) {
    (void)in_sizes; (void)n_in; (void)out_size;
    const float* x     = (const float*)d_in[0];
    const float* w     = (const float*)d_in[1];
    const float* convw = (const float*)d_in[2];
    const float* mod_w = (const float*)d_in[3];
    const float* mod_b = (const float*)d_in[4];
    float* out = (float*)d_out;

    unsigned char* ws = (unsigned char*)d_ws;
    const size_t OFF_STYLE = 0;
    const size_t OFF_S2 = 32768;
    const size_t OFF_D = OFF_S2 + 1048576;
    const size_t OFF_BIG = OFF_D + 32768;
    const size_t PER_B_W = (size_t)9 * COUT * CIN * 2; // 4,718,592 B
    const size_t PER_B_X = (size_t)HWSZ * CIN * 2;     // 4,194,304 B
    const size_t PER_B = PER_B_W + PER_B_X;

    if (ws_size < OFF_BIG + PER_B) return; // cannot run
    const size_t avail = ws_size - OFF_BIG;
    const int G = (avail >= 16 * PER_B) ? 16 : (avail >= 4 * PER_B ? 4 : 1);

    float* style = (float*)(ws + OFF_STYLE);
    float* s2    = (float*)(ws + OFF_S2);
    float* dd    = (float*)(ws + OFF_D);
    unsigned short* wmod = (unsigned short*)(ws + OFF_BIG);
    unsigned short* xT   = (unsigned short*)(ws + OFF_BIG + (size_t)G * PER_B_W);

    k_style<<<dim3(16), dim3(256), 0, stream>>>(w, mod_w, mod_b, style);
    k_s2<<<dim3(1024), dim3(256), 0, stream>>>(convw, s2);
    k_demod<<<dim3(16), dim3(256), 0, stream>>>(style, s2, dd);

    for (int b0 = 0; b0 < NB; b0 += G) {
        k_wmod<<<dim3(9, 8, 4), dim3(256), 0, stream>>>(convw, style, dd, wmod, b0, G);
        k_xt<<<dim3(G, 64, 8), dim3(256), 0, stream>>>(x, xT, b0);
        k_conv<<<dim3(16 * 4 * G), dim3(256), 0, stream>>>(xT, wmod, out, b0, G);
    }
}

// Round 12
// 393.593 us; speedup vs baseline: 1.5094x; 1.1084x over previous
//
#include <hip/hip_runtime.h>
#include <hip/hip_bf16.h>

#define NB    16
#define CIN   512
#define COUT  512
#define HH    64
#define WW    64
#define HWSZ  4096
#define WDIMN 512

typedef __attribute__((ext_vector_type(8))) short bf16x8;
typedef __attribute__((ext_vector_type(4))) float f32x4;

__device__ __forceinline__ unsigned short f2bf(float f) {
    unsigned int u = __float_as_uint(f);
    unsigned int lsb = (u >> 16) & 1u;
    u += 0x7fffu + lsb;               // round-to-nearest-even (finite inputs)
    return (unsigned short)(u >> 16);
}

__device__ __forceinline__ void gload_lds16(const void* g, void* l) {
    __builtin_amdgcn_global_load_lds(
        (const __attribute__((address_space(1))) unsigned char*)g,
        (__attribute__((address_space(3))) unsigned char*)l,
        16, 0, 0);
}

// ---------------- k1: style[b][ci] = coef_mod * (w @ mod_w) + mod_b + 1 ----------------
__global__ void k_style(const float* __restrict__ w, const float* __restrict__ mod_w,
                        const float* __restrict__ mod_b, float* __restrict__ style) {
    const int b = blockIdx.x, t = threadIdx.x;
    __shared__ float wl[WDIMN];
    wl[t] = w[b * WDIMN + t];
    wl[t + 256] = w[b * WDIMN + t + 256];
    __syncthreads();
    float a0 = 0.f, a1 = 0.f;
    const int c0 = t, c1 = t + 256;
    for (int j = 0; j < WDIMN; ++j) {
        const float wj = wl[j];
        a0 += wj * mod_w[j * CIN + c0];
        a1 += wj * mod_w[j * CIN + c1];
    }
    const float coef = 0.044194173824159216f; // 1/sqrt(512)
    style[b * CIN + c0] = coef * a0 + mod_b[c0] + 1.0f;
    style[b * CIN + c1] = coef * a1 + mod_b[c1] + 1.0f;
}

// ---------------- k2: s2[ci][co] = sum_taps conv_w^2 ----------------
__global__ void k_s2(const float* __restrict__ cw, float* __restrict__ s2) {
    const int i = blockIdx.x * 256 + threadIdx.x; // [ci*512+co]
    float a = 0.f;
#pragma unroll
    for (int tap = 0; tap < 9; ++tap) {
        const float v = cw[tap * (CIN * COUT) + i];
        a += v * v;
    }
    s2[i] = a;
}

// ---------------- k3: d[b][co] = rsqrt(coef^2 * sum_ci style^2 * s2 + 1e-8) ----------------
__global__ void k_demod(const float* __restrict__ style, const float* __restrict__ s2,
                        float* __restrict__ dd) {
    const int b = blockIdx.x, t = threadIdx.x;
    __shared__ float st2[CIN];
    {
        const float s0 = style[b * CIN + t], s1 = style[b * CIN + t + 256];
        st2[t] = s0 * s0;
        st2[t + 256] = s1 * s1;
    }
    __syncthreads();
    float a0 = 0.f, a1 = 0.f;
    for (int ci = 0; ci < CIN; ++ci) {
        const float sv = st2[ci];
        a0 += sv * s2[ci * COUT + t];
        a1 += sv * s2[ci * COUT + t + 256];
    }
    const float c2 = 1.0f / 4608.0f; // coef_conv^2
    dd[b * COUT + t] = rsqrtf(c2 * a0 + 1e-8f);
    dd[b * COUT + t + 256] = rsqrtf(c2 * a1 + 1e-8f);
}

// ---------------- k4: wmod[bbl][tap][co][ci] = bf16(conv_w * coef * style * d) ----------------
__global__ void k_wmod(const float* __restrict__ cw, const float* __restrict__ style,
                       const float* __restrict__ dd, unsigned short* __restrict__ wmod,
                       int b_start, int gcount) {
    const int tap = blockIdx.x;
    const int co0 = blockIdx.y * 64;
    const int ci0 = blockIdx.z * 128;
    const int t = threadIdx.x;

    __shared__ float tile[128][65]; // [ci][co], padded
    __shared__ float sst[16 * 128]; // style slice [bbl][128-ci-chunk]
    {
        const int j = t & 63, isub = t >> 6;
        for (int i = isub; i < 128; i += 4)
            tile[i][j] = cw[(size_t)tap * CIN * COUT + (size_t)(ci0 + i) * COUT + co0 + j];
    }
    for (int i = t; i < gcount * 128; i += 256)
        sst[i] = style[(b_start + (i >> 7)) * CIN + ci0 + (i & 127)];
    __syncthreads();

    const float coef = 0.014731391274719736f; // 1/sqrt(4608)
    const int cq = t & 31;        // ci quad: ci = ci0 + 4*cq + k
    const int rsub = t >> 5;      // 0..7
    const int totrows = gcount * 64;
    for (int g = rsub; g < totrows; g += 8) {
        const int bbl = g >> 6;
        const int co_r = g & 63;
        const int bg = b_start + bbl;
        const float dv = dd[bg * COUT + co0 + co_r] * coef;
        const float v0 = tile[4 * cq + 0][co_r] * sst[bbl * 128 + 4 * cq + 0] * dv;
        const float v1 = tile[4 * cq + 1][co_r] * sst[bbl * 128 + 4 * cq + 1] * dv;
        const float v2 = tile[4 * cq + 2][co_r] * sst[bbl * 128 + 4 * cq + 2] * dv;
        const float v3 = tile[4 * cq + 3][co_r] * sst[bbl * 128 + 4 * cq + 3] * dv;
        uint2 pk;
        pk.x = (unsigned int)f2bf(v0) | ((unsigned int)f2bf(v1) << 16);
        pk.y = (unsigned int)f2bf(v2) | ((unsigned int)f2bf(v3) << 16);
        *(uint2*)&wmod[((size_t)(bbl * 9 + tap) * COUT + co0 + co_r) * CIN + ci0 + 4 * cq] = pk;
    }
}

// ---------------- k5: xT[bbl][hw][ci] = bf16(x[b][ci][hw]) ----------------
// float4 global reads (16B/lane), LDS transpose, uint2 stores.
__global__ void k_xt(const float* __restrict__ x, unsigned short* __restrict__ xT, int b_start) {
    const int bbl = blockIdx.x;
    const int b = b_start + bbl;
    const int hw0 = blockIdx.y * 64;
    const int ci0 = blockIdx.z * 64;
    const int t = threadIdx.x;

    __shared__ float tile[64][65]; // [ci][hw], padded
    {
        const int q = t & 15;      // hw quad (4 floats)
        const int i0 = t >> 4;     // 0..15
        for (int i = i0; i < 64; i += 16) {
            const float4 v = *(const float4*)&x[(size_t)(b * CIN + ci0 + i) * HWSZ + hw0 + 4 * q];
            tile[i][4 * q + 0] = v.x;
            tile[i][4 * q + 1] = v.y;
            tile[i][4 * q + 2] = v.z;
            tile[i][4 * q + 3] = v.w;
        }
    }
    __syncthreads();

    const int cq = t & 15;   // ci quad within 64-chunk
    const int rs = t >> 4;   // 0..15
    for (int r = rs; r < 64; r += 16) {
        const float v0 = tile[4 * cq + 0][r];
        const float v1 = tile[4 * cq + 1][r];
        const float v2 = tile[4 * cq + 2][r];
        const float v3 = tile[4 * cq + 3][r];
        uint2 pk;
        pk.x = (unsigned int)f2bf(v0) | ((unsigned int)f2bf(v1) << 16);
        pk.y = (unsigned int)f2bf(v2) | ((unsigned int)f2bf(v3) << 16);
        *(uint2*)&xT[((size_t)bbl * HWSZ + hw0 + r) * CIN + ci0 + 4 * cq] = pk;
    }
}

// ---------------- k6: 9-tap implicit-GEMM conv, MFMA bf16, counted-vmcnt sync ----------
// ROUND-6 CHAMPION, verbatim. 128co x 128px tile (2 rows x 64 cols full width), BK=64,
// 66.5 KB LDS -> 2 blocks/CU, XCD-pinned grid. Per tap: {ds_read+MFMA free-scheduled}
// -> lgkm0 -> s_barrier -> issue X(cc+1)/A(g+2) -> vmcnt(4) (A(g+1)+X landed; A(g+2)
// stays in flight) -> s_barrier. Measured: 292 us, MfmaUtil 48%, FETCH 131 MB, 0 conflicts.
__global__ __launch_bounds__(256, 2)
void k_conv(const unsigned short* __restrict__ xT, const unsigned short* __restrict__ wmod,
            float* __restrict__ out, int b_start, int gcount) {
    int st, ct, bbl;
    {
        const int id = blockIdx.x;
        if (gcount == 16) {
            // hw assigns XCD = linear_id % 8; pin bbl (and its xT/wmod panels) to one XCD
            const int xcd = id & 7;
            const int slot = id >> 3;          // 0..255
            bbl = xcd + 8 * (slot >> 7);       // {xcd, xcd+8}
            const int rem = slot & 127;
            ct = rem >> 5;                     // 0..3
            st = rem & 31;
        } else {
            st = id & 31; ct = (id >> 5) & 3; bbl = id >> 7;
        }
    }
    const int b = b_start + bbl;
    const int r0 = st * 2;      // first output row
    const int co0 = ct * 128;

    const int t = threadIdx.x;
    const int lane = t & 63;
    const int wid = t >> 6;
    const int wrow = wid >> 1; // co half
    const int wcol = wid & 1;  // px half

    __shared__ __align__(16) unsigned char smem[4 * 66 * 128 + 2 * 128 * 128];
    unsigned char* Xs = smem;                 // [(row*66+col)][128B]
    unsigned char* As = smem + 4 * 66 * 128;  // 2 x [co][128B]

    const f32x4 fzero = {0.f, 0.f, 0.f, 0.f};

    // one-time zeroing: pad columns (0, 65) for all 4 rows, and out-of-image halo rows
    if (t < 64) {
        const int s = t >> 3;                    // 8 pad slots
        const int row = s >> 1, col = (s & 1) ? 65 : 0;
        *(f32x4*)(Xs + (row * 66 + col) * 128 + (t & 7) * 16) = fzero;
    }
    if (r0 == 0) {
        for (int idx = t; idx < 66 * 8; idx += 256)
            *(f32x4*)(Xs + (idx >> 3) * 128 + (idx & 7) * 16) = fzero;
    }
    if (r0 == 62) {
        for (int idx = t; idx < 66 * 8; idx += 256)
            *(f32x4*)(Xs + (3 * 66 + (idx >> 3)) * 128 + (idx & 7) * 16) = fzero;
    }

    f32x4 acc[4][4];
#pragma unroll
    for (int i = 0; i < 4; ++i)
#pragma unroll
        for (int j = 0; j < 4; ++j) acc[i][j] = fzero;

    const size_t xTbase = (size_t)bbl * HWSZ * CIN;

    auto stageA = [&](int gidx) { // load A(gidx) into slot gidx&1
        const int tap2 = gidx % 9, cc2 = gidx / 9;
        const unsigned short* gb = wmod + ((size_t)(bbl * 9 + tap2) * COUT + co0) * CIN + cc2 * 64;
        unsigned char* dbase = As + (gidx & 1) * 16384;
#pragma unroll
        for (int i = 0; i < 4; ++i) {
            const int la = wid + 4 * i;                 // 0..15
            const int row = la * 8 + (lane >> 3);       // 0..127 (co)
            const int kb = ((lane & 7) * 16) ^ ((row & 7) << 4); // pre-swizzled source
            gload_lds16((const unsigned char*)(gb + (size_t)row * CIN) + kb,
                        dbase + la * 1024);
        }
    };
    auto stageX = [&](int ccn) {
        const int ci0 = ccn * 64;
#pragma unroll
        for (int i = 0; i < 8; ++i) {
            const int li = wid + 4 * i;      // 0..31
            const int row = li >> 3;         // 0..3
            const int c0 = 1 + (li & 7) * 8; // 1,9,...,57
            const int ih = r0 - 1 + row;
            if (ih >= 0 && ih < HH) {
                const int col = c0 + (lane >> 3);     // 1..64
                const int pxidx = row * 66 + col;
                const int kb = ((lane & 7) * 16) ^ ((pxidx & 7) << 4);
                gload_lds16((const unsigned char*)(xT + xTbase + (size_t)(ih * WW + col - 1) * CIN + ci0) + kb,
                            Xs + (row * 66 + c0) * 128);
            }
        }
    };

    // prologue: X(0), A(0), A(1); wait X+A(0) (A(1) may fly) + own ds_writes; barrier
    stageX(0);
    stageA(0);
    stageA(1);
    asm volatile("s_waitcnt vmcnt(4) lgkmcnt(0)" ::: "memory");
    __builtin_amdgcn_s_barrier();

    for (int cc = 0; cc < 8; ++cc) {
#pragma unroll
        for (int tap = 0; tap < 9; ++tap) {
            const int g = cc * 9 + tap;
            const unsigned char* Ab = As + (g & 1) * 16384;
            const int dh = tap / 3 - 1, dw = tap % 3 - 1;

            // ds_read + MFMA, compiler-scheduled (fine-grained lgkmcnt interleave)
#pragma unroll
            for (int k32 = 0; k32 < 2; ++k32) {
                bf16x8 af[4], bfv[4];
#pragma unroll
                for (int ma = 0; ma < 4; ++ma) {
                    const int co_r = wrow * 64 + ma * 16 + (lane & 15);
                    const int kb = (k32 * 64 + (lane >> 4) * 16) ^ ((co_r & 7) << 4);
                    af[ma] = *(const bf16x8*)(Ab + co_r * 128 + kb);
                }
#pragma unroll
                for (int nb = 0; nb < 4; ++nb) {
                    const int px = wcol * 64 + nb * 16 + (lane & 15);
                    const int trow = (px >> 6) + 1 + dh;   // 0..3
                    const int tcol = (px & 63) + 1 + dw;   // 0..65
                    const int pxidx = trow * 66 + tcol;
                    const int kb = (k32 * 64 + (lane >> 4) * 16) ^ ((pxidx & 7) << 4);
                    bfv[nb] = *(const bf16x8*)(Xs + pxidx * 128 + kb);
                }
#pragma unroll
                for (int ma = 0; ma < 4; ++ma)
#pragma unroll
                    for (int nb = 0; nb < 4; ++nb)
                        acc[ma][nb] = __builtin_amdgcn_mfma_f32_16x16x32_bf16(
                            af[ma], bfv[nb], acc[ma][nb], 0, 0, 0);
            }

            // barrier #1: this wave's LDS reads retired; all waves done with slot/Xs
            asm volatile("s_waitcnt lgkmcnt(0)" ::: "memory");
            __builtin_amdgcn_s_barrier();

            // prefetch: X(cc+1) first (so vmcnt(4) covers it), then A(g+2) into slot g&1
            if (tap == 8 && cc < 7) stageX(cc + 1);
            if (g < 70) stageA(g + 2);

            // wait: A(g+1) (+X if boundary) landed; A(g+2) stays in flight
            if (g == 70) asm volatile("s_waitcnt vmcnt(0)" ::: "memory");
            else         asm volatile("s_waitcnt vmcnt(4)" ::: "memory");
            __builtin_amdgcn_s_barrier();   // barrier #2: next operands visible to all
        }
    }

    // epilogue: C/D layout col=lane&15 (px/N), row=(lane>>4)*4+reg (co/M)
#pragma unroll
    for (int ma = 0; ma < 4; ++ma) {
        const int co = co0 + wrow * 64 + ma * 16 + ((lane >> 4) << 2);
#pragma unroll
        for (int nb = 0; nb < 4; ++nb) {
            const int px = wcol * 64 + nb * 16 + (lane & 15);
            const int oh = r0 + (px >> 6);
            const int ow = px & 63;
            float* o = out + (((size_t)b * COUT + co) * HH + oh) * WW + ow;
#pragma unroll
            for (int jj = 0; jj < 4; ++jj) o[(size_t)jj * HWSZ] = acc[ma][nb][jj];
        }
    }
}

extern "C" void kernel_launch(void* const* d_in, const int* in_sizes, int n_in,
                              void* d_out, int out_size, void* d_ws, size_t ws_size,
                              hipStream_t stream) {
    (void)in_sizes; (void)n_in; (void)out_size;
    const float* x     = (const float*)d_in[0];
    const float* w     = (const float*)d_in[1];
    const float* convw = (const float*)d_in[2];
    const float* mod_w = (const float*)d_in[3];
    const float* mod_b = (const float*)d_in[4];
    float* out = (float*)d_out;

    unsigned char* ws = (unsigned char*)d_ws;
    const size_t OFF_STYLE = 0;
    const size_t OFF_S2 = 32768;
    const size_t OFF_D = OFF_S2 + 1048576;
    const size_t OFF_BIG = OFF_D + 32768;
    const size_t PER_B_W = (size_t)9 * COUT * CIN * 2; // 4,718,592 B
    const size_t PER_B_X = (size_t)HWSZ * CIN * 2;     // 4,194,304 B
    const size_t PER_B = PER_B_W + PER_B_X;

    if (ws_size < OFF_BIG + PER_B) return; // cannot run
    const size_t avail = ws_size - OFF_BIG;
    const int G = (avail >= 16 * PER_B) ? 16 : (avail >= 4 * PER_B ? 4 : 1);

    float* style = (float*)(ws + OFF_STYLE);
    float* s2    = (float*)(ws + OFF_S2);
    float* dd    = (float*)(ws + OFF_D);
    unsigned short* wmod = (unsigned short*)(ws + OFF_BIG);
    unsigned short* xT   = (unsigned short*)(ws + OFF_BIG + (size_t)G * PER_B_W);

    k_style<<<dim3(16), dim3(256), 0, stream>>>(w, mod_w, mod_b, style);
    k_s2<<<dim3(1024), dim3(256), 0, stream>>>(convw, s2);
    k_demod<<<dim3(16), dim3(256), 0, stream>>>(style, s2, dd);

    for (int b0 = 0; b0 < NB; b0 += G) {
        k_wmod<<<dim3(9, 8, 4), dim3(256), 0, stream>>>(convw, style, dd, wmod, b0, G);
        k_xt<<<dim3(G, 64, 8), dim3(256), 0, stream>>>(x, xT, b0);
        k_conv<<<dim3(32 * 4 * G), dim3(256), 0, stream>>>(xT, wmod, out, b0, G);
    }
}

// Round 13
// 384.700 us; speedup vs baseline: 1.5443x; 1.0231x over previous
//
#include <hip/hip_runtime.h>
#include <hip/hip_bf16.h>

#define NB    16
#define CIN   512
#define COUT  512
#define HH    64
#define WW    64
#define HWSZ  4096
#define WDIMN 512

typedef __attribute__((ext_vector_type(8))) short bf16x8;
typedef __attribute__((ext_vector_type(4))) float f32x4;

__device__ __forceinline__ unsigned short f2bf(float f) {
    unsigned int u = __float_as_uint(f);
    unsigned int lsb = (u >> 16) & 1u;
    u += 0x7fffu + lsb;               // round-to-nearest-even (finite inputs)
    return (unsigned short)(u >> 16);
}

__device__ __forceinline__ void gload_lds16(const void* g, void* l) {
    __builtin_amdgcn_global_load_lds(
        (const __attribute__((address_space(1))) unsigned char*)g,
        (__attribute__((address_space(3))) unsigned char*)l,
        16, 0, 0);
}

// ---------------- k1: style[b][ci] = coef_mod * (w @ mod_w) + mod_b + 1 ----------------
__global__ void k_style(const float* __restrict__ w, const float* __restrict__ mod_w,
                        const float* __restrict__ mod_b, float* __restrict__ style) {
    const int b = blockIdx.x, t = threadIdx.x;
    __shared__ float wl[WDIMN];
    wl[t] = w[b * WDIMN + t];
    wl[t + 256] = w[b * WDIMN + t + 256];
    __syncthreads();
    float a0 = 0.f, a1 = 0.f;
    const int c0 = t, c1 = t + 256;
    for (int j = 0; j < WDIMN; ++j) {
        const float wj = wl[j];
        a0 += wj * mod_w[j * CIN + c0];
        a1 += wj * mod_w[j * CIN + c1];
    }
    const float coef = 0.044194173824159216f; // 1/sqrt(512)
    style[b * CIN + c0] = coef * a0 + mod_b[c0] + 1.0f;
    style[b * CIN + c1] = coef * a1 + mod_b[c1] + 1.0f;
}

// ---------------- k2: s2[ci][co] = sum_taps conv_w^2 ----------------
__global__ void k_s2(const float* __restrict__ cw, float* __restrict__ s2) {
    const int i = blockIdx.x * 256 + threadIdx.x; // [ci*512+co]
    float a = 0.f;
#pragma unroll
    for (int tap = 0; tap < 9; ++tap) {
        const float v = cw[tap * (CIN * COUT) + i];
        a += v * v;
    }
    s2[i] = a;
}

// ---------------- k3: d[b][co] = rsqrt(coef^2 * sum_ci style^2 * s2 + 1e-8) ----------------
__global__ void k_demod(const float* __restrict__ style, const float* __restrict__ s2,
                        float* __restrict__ dd) {
    const int b = blockIdx.x, t = threadIdx.x;
    __shared__ float st2[CIN];
    {
        const float s0 = style[b * CIN + t], s1 = style[b * CIN + t + 256];
        st2[t] = s0 * s0;
        st2[t + 256] = s1 * s1;
    }
    __syncthreads();
    float a0 = 0.f, a1 = 0.f;
    for (int ci = 0; ci < CIN; ++ci) {
        const float sv = st2[ci];
        a0 += sv * s2[ci * COUT + t];
        a1 += sv * s2[ci * COUT + t + 256];
    }
    const float c2 = 1.0f / 4608.0f; // coef_conv^2
    dd[b * COUT + t] = rsqrtf(c2 * a0 + 1e-8f);
    dd[b * COUT + t + 256] = rsqrtf(c2 * a1 + 1e-8f);
}

// ---------------- k4: wmod[bbl][tap][co][ci] = bf16(conv_w * coef * style * d) ----------------
__global__ void k_wmod(const float* __restrict__ cw, const float* __restrict__ style,
                       const float* __restrict__ dd, unsigned short* __restrict__ wmod,
                       int b_start, int gcount) {
    const int tap = blockIdx.x;
    const int co0 = blockIdx.y * 64;
    const int ci0 = blockIdx.z * 128;
    const int t = threadIdx.x;

    __shared__ float tile[128][65]; // [ci][co], padded
    __shared__ float sst[16 * 128]; // style slice [bbl][128-ci-chunk]
    {
        const int j = t & 63, isub = t >> 6;
        for (int i = isub; i < 128; i += 4)
            tile[i][j] = cw[(size_t)tap * CIN * COUT + (size_t)(ci0 + i) * COUT + co0 + j];
    }
    for (int i = t; i < gcount * 128; i += 256)
        sst[i] = style[(b_start + (i >> 7)) * CIN + ci0 + (i & 127)];
    __syncthreads();

    const float coef = 0.014731391274719736f; // 1/sqrt(4608)
    const int cq = t & 31;        // ci quad: ci = ci0 + 4*cq + k
    const int rsub = t >> 5;      // 0..7
    const int totrows = gcount * 64;
    for (int g = rsub; g < totrows; g += 8) {
        const int bbl = g >> 6;
        const int co_r = g & 63;
        const int bg = b_start + bbl;
        const float dv = dd[bg * COUT + co0 + co_r] * coef;
        const float v0 = tile[4 * cq + 0][co_r] * sst[bbl * 128 + 4 * cq + 0] * dv;
        const float v1 = tile[4 * cq + 1][co_r] * sst[bbl * 128 + 4 * cq + 1] * dv;
        const float v2 = tile[4 * cq + 2][co_r] * sst[bbl * 128 + 4 * cq + 2] * dv;
        const float v3 = tile[4 * cq + 3][co_r] * sst[bbl * 128 + 4 * cq + 3] * dv;
        uint2 pk;
        pk.x = (unsigned int)f2bf(v0) | ((unsigned int)f2bf(v1) << 16);
        pk.y = (unsigned int)f2bf(v2) | ((unsigned int)f2bf(v3) << 16);
        *(uint2*)&wmod[((size_t)(bbl * 9 + tap) * COUT + co0 + co_r) * CIN + ci0 + 4 * cq] = pk;
    }
}

// ---------------- k5: xT[bbl][hw][ci] = bf16(x[b][ci][hw]) ----------------
// float4 global reads (16B/lane), LDS transpose, uint2 stores.
__global__ void k_xt(const float* __restrict__ x, unsigned short* __restrict__ xT, int b_start) {
    const int bbl = blockIdx.x;
    const int b = b_start + bbl;
    const int hw0 = blockIdx.y * 64;
    const int ci0 = blockIdx.z * 64;
    const int t = threadIdx.x;

    __shared__ float tile[64][65]; // [ci][hw], padded
    {
        const int q = t & 15;      // hw quad (4 floats)
        const int i0 = t >> 4;     // 0..15
        for (int i = i0; i < 64; i += 16) {
            const float4 v = *(const float4*)&x[(size_t)(b * CIN + ci0 + i) * HWSZ + hw0 + 4 * q];
            tile[i][4 * q + 0] = v.x;
            tile[i][4 * q + 1] = v.y;
            tile[i][4 * q + 2] = v.z;
            tile[i][4 * q + 3] = v.w;
        }
    }
    __syncthreads();

    const int cq = t & 15;   // ci quad within 64-chunk
    const int rs = t >> 4;   // 0..15
    for (int r = rs; r < 64; r += 16) {
        const float v0 = tile[4 * cq + 0][r];
        const float v1 = tile[4 * cq + 1][r];
        const float v2 = tile[4 * cq + 2][r];
        const float v3 = tile[4 * cq + 3][r];
        uint2 pk;
        pk.x = (unsigned int)f2bf(v0) | ((unsigned int)f2bf(v1) << 16);
        pk.y = (unsigned int)f2bf(v2) | ((unsigned int)f2bf(v3) << 16);
        *(uint2*)&xT[((size_t)bbl * HWSZ + hw0 + r) * CIN + ci0 + 4 * cq] = pk;
    }
}

// ---------------- k6: 9-tap implicit-GEMM conv, split-read counted-vmcnt sync ----------
// Round-6 champion geometry (128co x 128px, 66.5 KB LDS, 2 blocks/CU, XCD-pinned).
// Schedule change (taps 0-7): A-slot's ONLY readers are the af ds_reads, so bar1 moves
// right after them — stageA(g+2) then overlaps the bfv reads + MFMA cluster instead of
// sitting on the serial path. Tap 8 keeps the original order (stageX overwrites Xs,
// whose readers are the bfv reads). vmcnt invariant unchanged: A(g+2) alone in flight
// at bar2 (gload_lds cannot cross the "memory"-clobber asm waits).
__global__ __launch_bounds__(256, 2)
void k_conv(const unsigned short* __restrict__ xT, const unsigned short* __restrict__ wmod,
            float* __restrict__ out, int b_start, int gcount) {
    int st, ct, bbl;
    {
        const int id = blockIdx.x;
        if (gcount == 16) {
            // hw assigns XCD = linear_id % 8; pin bbl (and its xT/wmod panels) to one XCD
            const int xcd = id & 7;
            const int slot = id >> 3;          // 0..255
            bbl = xcd + 8 * (slot >> 7);       // {xcd, xcd+8}
            const int rem = slot & 127;
            ct = rem >> 5;                     // 0..3
            st = rem & 31;
        } else {
            st = id & 31; ct = (id >> 5) & 3; bbl = id >> 7;
        }
    }
    const int b = b_start + bbl;
    const int r0 = st * 2;      // first output row
    const int co0 = ct * 128;

    const int t = threadIdx.x;
    const int lane = t & 63;
    const int wid = t >> 6;
    const int wrow = wid >> 1; // co half
    const int wcol = wid & 1;  // px half

    __shared__ __align__(16) unsigned char smem[4 * 66 * 128 + 2 * 128 * 128];
    unsigned char* Xs = smem;                 // [(row*66+col)][128B]
    unsigned char* As = smem + 4 * 66 * 128;  // 2 x [co][128B]

    const f32x4 fzero = {0.f, 0.f, 0.f, 0.f};

    // one-time zeroing: pad columns (0, 65) for all 4 rows, and out-of-image halo rows
    if (t < 64) {
        const int s = t >> 3;                    // 8 pad slots
        const int row = s >> 1, col = (s & 1) ? 65 : 0;
        *(f32x4*)(Xs + (row * 66 + col) * 128 + (t & 7) * 16) = fzero;
    }
    if (r0 == 0) {
        for (int idx = t; idx < 66 * 8; idx += 256)
            *(f32x4*)(Xs + (idx >> 3) * 128 + (idx & 7) * 16) = fzero;
    }
    if (r0 == 62) {
        for (int idx = t; idx < 66 * 8; idx += 256)
            *(f32x4*)(Xs + (3 * 66 + (idx >> 3)) * 128 + (idx & 7) * 16) = fzero;
    }

    f32x4 acc[4][4];
#pragma unroll
    for (int i = 0; i < 4; ++i)
#pragma unroll
        for (int j = 0; j < 4; ++j) acc[i][j] = fzero;

    const size_t xTbase = (size_t)bbl * HWSZ * CIN;

    auto stageA = [&](int gidx) { // load A(gidx) into slot gidx&1
        const int tap2 = gidx % 9, cc2 = gidx / 9;
        const unsigned short* gb = wmod + ((size_t)(bbl * 9 + tap2) * COUT + co0) * CIN + cc2 * 64;
        unsigned char* dbase = As + (gidx & 1) * 16384;
#pragma unroll
        for (int i = 0; i < 4; ++i) {
            const int la = wid + 4 * i;                 // 0..15
            const int row = la * 8 + (lane >> 3);       // 0..127 (co)
            const int kb = ((lane & 7) * 16) ^ ((row & 7) << 4); // pre-swizzled source
            gload_lds16((const unsigned char*)(gb + (size_t)row * CIN) + kb,
                        dbase + la * 1024);
        }
    };
    auto stageX = [&](int ccn) {
        const int ci0 = ccn * 64;
#pragma unroll
        for (int i = 0; i < 8; ++i) {
            const int li = wid + 4 * i;      // 0..31
            const int row = li >> 3;         // 0..3
            const int c0 = 1 + (li & 7) * 8; // 1,9,...,57
            const int ih = r0 - 1 + row;
            if (ih >= 0 && ih < HH) {
                const int col = c0 + (lane >> 3);     // 1..64
                const int pxidx = row * 66 + col;
                const int kb = ((lane & 7) * 16) ^ ((pxidx & 7) << 4);
                gload_lds16((const unsigned char*)(xT + xTbase + (size_t)(ih * WW + col - 1) * CIN + ci0) + kb,
                            Xs + (row * 66 + c0) * 128);
            }
        }
    };

    // per-thread constant af/bfv index pieces
    const int laneco = lane & 15;
    const int koff = (lane >> 4) * 16;

    // prologue: X(0), A(0), A(1); wait X+A(0) (A(1) may fly) + own ds_writes; barrier
    stageX(0);
    stageA(0);
    stageA(1);
    asm volatile("s_waitcnt vmcnt(4) lgkmcnt(0)" ::: "memory");
    __builtin_amdgcn_s_barrier();

    for (int cc = 0; cc < 8; ++cc) {
#pragma unroll
        for (int tap = 0; tap < 9; ++tap) {
            const int g = cc * 9 + tap;
            const unsigned char* Ab = As + (g & 1) * 16384;
            const int dh = tap / 3 - 1, dw = tap % 3 - 1;

            bf16x8 af[2][4];
            // af reads: BOTH k32 halves upfront (sole readers of slot g&1)
#pragma unroll
            for (int k32 = 0; k32 < 2; ++k32)
#pragma unroll
                for (int ma = 0; ma < 4; ++ma) {
                    const int co_r = wrow * 64 + ma * 16 + laneco;
                    const int kb = (k32 * 64 + koff) ^ ((co_r & 7) << 4);
                    af[k32][ma] = *(const bf16x8*)(Ab + co_r * 128 + kb);
                }

            if (tap < 8) {
                // bar1 early: only af reads must retire before slot g&1 is overwritten
                asm volatile("s_waitcnt lgkmcnt(0)" ::: "memory");
                __builtin_amdgcn_s_barrier();
                stageA(g + 2);   // overlaps bfv reads + MFMA below
            }

            // bfv reads + MFMA, compiler-scheduled (fine-grained lgkmcnt interleave)
#pragma unroll
            for (int k32 = 0; k32 < 2; ++k32) {
                bf16x8 bfv[4];
#pragma unroll
                for (int nb = 0; nb < 4; ++nb) {
                    const int px = wcol * 64 + nb * 16 + laneco;
                    const int trow = (px >> 6) + 1 + dh;   // 0..3
                    const int tcol = (px & 63) + 1 + dw;   // 0..65
                    const int pxidx = trow * 66 + tcol;
                    const int kb = (k32 * 64 + koff) ^ ((pxidx & 7) << 4);
                    bfv[nb] = *(const bf16x8*)(Xs + pxidx * 128 + kb);
                }
#pragma unroll
                for (int ma = 0; ma < 4; ++ma)
#pragma unroll
                    for (int nb = 0; nb < 4; ++nb)
                        acc[ma][nb] = __builtin_amdgcn_mfma_f32_16x16x32_bf16(
                            af[k32][ma], bfv[nb], acc[ma][nb], 0, 0, 0);
            }

            if (tap < 8) {
                // bar2: A(g+1) landed (A(g+2) stays in flight)
                asm volatile("s_waitcnt vmcnt(4)" ::: "memory");
                __builtin_amdgcn_s_barrier();
            } else {
                // cc boundary (original order): all LDS reads retired, then stage X/A
                asm volatile("s_waitcnt lgkmcnt(0)" ::: "memory");
                __builtin_amdgcn_s_barrier();
                if (cc < 7) stageX(cc + 1);
                if (g < 70) stageA(g + 2);
                if (g == 70) asm volatile("s_waitcnt vmcnt(0)" ::: "memory");
                else         asm volatile("s_waitcnt vmcnt(4)" ::: "memory");
                __builtin_amdgcn_s_barrier();
            }
        }
    }

    // epilogue: C/D layout col=lane&15 (px/N), row=(lane>>4)*4+reg (co/M)
#pragma unroll
    for (int ma = 0; ma < 4; ++ma) {
        const int co = co0 + wrow * 64 + ma * 16 + ((lane >> 4) << 2);
#pragma unroll
        for (int nb = 0; nb < 4; ++nb) {
            const int px = wcol * 64 + nb * 16 + (lane & 15);
            const int oh = r0 + (px >> 6);
            const int ow = px & 63;
            float* o = out + (((size_t)b * COUT + co) * HH + oh) * WW + ow;
#pragma unroll
            for (int jj = 0; jj < 4; ++jj) o[(size_t)jj * HWSZ] = acc[ma][nb][jj];
        }
    }
}

extern "C" void kernel_launch(void* const* d_in, const int* in_sizes, int n_in,
                              void* d_out, int out_size, void* d_ws, size_t ws_size,
                              hipStream_t stream) {
    (void)in_sizes; (void)n_in; (void)out_size;
    const float* x     = (const float*)d_in[0];
    const float* w     = (const float*)d_in[1];
    const float* convw = (const float*)d_in[2];
    const float* mod_w = (const float*)d_in[3];
    const float* mod_b = (const float*)d_in[4];
    float* out = (float*)d_out;

    unsigned char* ws = (unsigned char*)d_ws;
    const size_t OFF_STYLE = 0;
    const size_t OFF_S2 = 32768;
    const size_t OFF_D = OFF_S2 + 1048576;
    const size_t OFF_BIG = OFF_D + 32768;
    const size_t PER_B_W = (size_t)9 * COUT * CIN * 2; // 4,718,592 B
    const size_t PER_B_X = (size_t)HWSZ * CIN * 2;     // 4,194,304 B
    const size_t PER_B = PER_B_W + PER_B_X;

    if (ws_size < OFF_BIG + PER_B) return; // cannot run
    const size_t avail = ws_size - OFF_BIG;
    const int G = (avail >= 16 * PER_B) ? 16 : (avail >= 4 * PER_B ? 4 : 1);

    float* style = (float*)(ws + OFF_STYLE);
    float* s2    = (float*)(ws + OFF_S2);
    float* dd    = (float*)(ws + OFF_D);
    unsigned short* wmod = (unsigned short*)(ws + OFF_BIG);
    unsigned short* xT   = (unsigned short*)(ws + OFF_BIG + (size_t)G * PER_B_W);

    k_style<<<dim3(16), dim3(256), 0, stream>>>(w, mod_w, mod_b, style);
    k_s2<<<dim3(1024), dim3(256), 0, stream>>>(convw, s2);
    k_demod<<<dim3(16), dim3(256), 0, stream>>>(style, s2, dd);

    for (int b0 = 0; b0 < NB; b0 += G) {
        k_wmod<<<dim3(9, 8, 4), dim3(256), 0, stream>>>(convw, style, dd, wmod, b0, G);
        k_xt<<<dim3(G, 64, 8), dim3(256), 0, stream>>>(x, xT, b0);
        k_conv<<<dim3(32 * 4 * G), dim3(256), 0, stream>>>(xT, wmod, out, b0, G);
    }
}